// Round 1
// 521.029 us; speedup vs baseline: 1.1963x; 1.1963x over previous
//
#include <hip/hip_runtime.h>
#include <math.h>
#include <stdint.h>

// Bayesian DAG marginal propagation, N=4096, K=14 parents, C=2^14 configs.
//
// v3: straggler-deferred fold. The kernel is dependency-latency bound
// (HBM 5%, VALU 8%, MFMA 0): runtime = DAG critical path (~200-300 links)
// x per-link latency. v2 paid, per link, AFTER the last parent flag landed:
// poll-detect + 2 x 16-wave barriers + ~30 fold FMAs + 10 shuffles + store.
// S is multilinear in the 14 parent probs and the fold network is
// commutative per dimension, so v3 waits only for >=13 of 14 parents,
// pre-folds the 13 ready dimensions (skipping the straggler's dim in its
// tier: register bits / lane bits / wave bits -> a 2-value pair), and the
// critical tail becomes: tight-poll straggler + ONE fma + store. All
// barriers and fold work overlap the straggler's latency.
//
// Also: no s_sleep in the poll (tighter detection), parent indices for the
// next node prefetched into wave-0 registers, flags already seen ready are
// not re-loaded, flag store issued before out[] store.
//
// Flag word IS the payload (parent marginal probability S; children clip to
// [1e-6, 1-1e-6] reproducing the reference's log-space clip chain).
// Sentinel 0x7F7F7F7F = 3.39e38 unreachable (S <= 16384). Relaxed
// agent-scope atomics suffice: no separate data to order.

#define NN     4096
#define KK     14
#define CC     16384
#define NROOTS 64
#define NBLK   256
#define NTHR   1024
#define PT     (CC / NTHR)   // 16 elements per thread
#define SENTIN 0x7F7F7F7Fu

// FOLD2(p, x0, x1): x0 = partial with this config bit = 0, x1 = bit = 1.
#define FOLD2(p, x0, x1) fmaf((p), (x1) - (x0), (x0))
// Fold 8 values over 3 bits; pA = lowest-stride bit's parent, then pB, pC.
#define FOLD8(pA, pB, pC, s0,s1,s2,s3,s4,s5,s6,s7) \
    FOLD2(pC, FOLD2(pB, FOLD2(pA, s0, s1), FOLD2(pA, s2, s3)), \
              FOLD2(pB, FOLD2(pA, s4, s5), FOLD2(pA, s6, s7)))

__global__ __launch_bounds__(NTHR, 4) void bayes_dag_kernel(
    const float* __restrict__ logits,
    const int*   __restrict__ parents,
    float*       __restrict__ out,
    unsigned*    __restrict__ flagv)   // N words: float bits of marginal prob
{
    __shared__ float pvals[KK];          // clipped parent probabilities
    __shared__ int   sSlotLds;           // straggler slot (0..13) or -1
    __shared__ int   sParLds;            // straggler parent node index
    __shared__ float redA[NTHR / 64];    // per-wave partial (straggler bit=0)
    __shared__ float redB[NTHR / 64];    // per-wave partial (straggler bit=1)

    const int tid  = threadIdx.x;
    const int lane = tid & 63;
    const int wv   = tid >> 6;
    const float LOG2E = 1.4426950408889634f;

    int node = blockIdx.x;
    if (node < NROOTS) {
        if (tid == 0) {
            float x = logits[(size_t)node * CC];
            float p = __builtin_amdgcn_rcpf(1.f + exp2f(-x * LOG2E));
            __hip_atomic_store(&flagv[node], __float_as_uint(p),
                               __ATOMIC_RELAXED, __HIP_MEMORY_SCOPE_AGENT);
            out[node] = p;
        }
        node += NBLK;
    }

    // preload first row: c = m*NTHR + tid (fully coalesced dwords)
    float xs[PT];
    {
        const float* row = logits + (size_t)node * CC;
        #pragma unroll
        for (int m = 0; m < PT; ++m) xs[m] = row[m * NTHR + tid];
    }
    // wave 0 keeps its parent indices in registers (lane k holds parent k)
    int pcur = 0;
    if (wv == 0 && lane < KK) pcur = parents[node * KK + lane];

    for (; node < NN; node += NBLK) {
        const int nxt    = node + NBLK;
        const int nclamp = (nxt < NN) ? nxt : node;

        // ---- issue prefetch of the next node's row (in flight during spin) ----
        const float* nrow = logits + (size_t)nclamp * CC;
        float xn[PT];
        #pragma unroll
        for (int m = 0; m < PT; ++m) xn[m] = nrow[m * NTHR + tid];

        // ---- parent-independent work: sigmoid of current row ----
        float sig[PT];
        #pragma unroll
        for (int m = 0; m < PT; ++m)
            sig[m] = __builtin_amdgcn_rcpf(1.f + exp2f(-xs[m] * LOG2E));

        // ---- wave 0: spin until >=13 of 14 parents ready; find straggler ----
        if (wv == 0) {
            unsigned v = SENTIN;
            unsigned long long rdy;
            int guard = 0;
            for (;;) {
                if (lane < KK && v == SENTIN)
                    v = __hip_atomic_load(&flagv[pcur], __ATOMIC_RELAXED,
                                          __HIP_MEMORY_SCOPE_AGENT);
                rdy = __ballot(lane >= KK || v != SENTIN);
                if (__popcll(rdy) >= 63) break;      // <=1 parent missing
                if (++guard > (1 << 22)) break;      // visible-failure escape
            }
            unsigned long long miss = (~rdy) & 0x3FFFull;
            int s  = miss ? __builtin_ctzll(miss) : -1;
            int sp = __shfl(pcur, (s < 0) ? 0 : s, 64);
            if (lane == 0) { sSlotLds = s; sParLds = sp; }
            if (lane < KK) {
                float pf = __uint_as_float(v);       // straggler lane: garbage, never read
                pvals[lane] = fminf(fmaxf(pf, 1e-6f), 1.f - 1e-6f);
            }
            // prefetch next node's parent indices (lands during fold/final-poll)
            if (lane < KK) pcur = parents[nclamp * KK + lane];
        }
        __syncthreads();

        const int s = sSlotLds;
        float pv[KK];
        #pragma unroll
        for (int k = 0; k < KK; ++k) pv[k] = pvals[k];

        // ---- register-tier folds: m bit j <-> c bit 10+j <-> parent 3-j ----
        // If straggler is parent 0..3, skip its bit: two half-folds -> pair.
        float acc, acc1 = 0.f;
        const bool regPair = (s >= 0 && s < 4);
        switch (s) {
            case 0:  // skip m bit 3
                acc  = FOLD8(pv[3],pv[2],pv[1], sig[0],sig[1],sig[2],sig[3],sig[4],sig[5],sig[6],sig[7]);
                acc1 = FOLD8(pv[3],pv[2],pv[1], sig[8],sig[9],sig[10],sig[11],sig[12],sig[13],sig[14],sig[15]);
                break;
            case 1:  // skip m bit 2
                acc  = FOLD8(pv[3],pv[2],pv[0], sig[0],sig[1],sig[2],sig[3],sig[8],sig[9],sig[10],sig[11]);
                acc1 = FOLD8(pv[3],pv[2],pv[0], sig[4],sig[5],sig[6],sig[7],sig[12],sig[13],sig[14],sig[15]);
                break;
            case 2:  // skip m bit 1
                acc  = FOLD8(pv[3],pv[1],pv[0], sig[0],sig[1],sig[4],sig[5],sig[8],sig[9],sig[12],sig[13]);
                acc1 = FOLD8(pv[3],pv[1],pv[0], sig[2],sig[3],sig[6],sig[7],sig[10],sig[11],sig[14],sig[15]);
                break;
            case 3:  // skip m bit 0
                acc  = FOLD8(pv[2],pv[1],pv[0], sig[0],sig[2],sig[4],sig[6],sig[8],sig[10],sig[12],sig[14]);
                acc1 = FOLD8(pv[2],pv[1],pv[0], sig[1],sig[3],sig[5],sig[7],sig[9],sig[11],sig[13],sig[15]);
                break;
            default: // full 4-level fold (straggler elsewhere, or none)
                acc = FOLD2(pv[0],
                        FOLD8(pv[3],pv[2],pv[1], sig[0],sig[1],sig[2],sig[3],sig[4],sig[5],sig[6],sig[7]),
                        FOLD8(pv[3],pv[2],pv[1], sig[8],sig[9],sig[10],sig[11],sig[12],sig[13],sig[14],sig[15]));
                break;
        }

        // ---- lane-tier folds: lane bit t <-> c bit t <-> parent 13-t ----
        const int st = (s >= 8) ? (13 - s) : -1;   // lane bit to skip
        #pragma unroll
        for (int t = 0; t < 6; ++t) {
            if (t == st) continue;                 // block-uniform branch
            const float p = pv[13 - t];
            {
                float other = __shfl_xor(acc, 1 << t, 64);
                bool  bit   = (lane >> t) & 1;
                float a = bit ? other : acc;
                float b = bit ? acc : other;
                acc = fmaf(p, b - a, a);
            }
            if (regPair) {
                float other = __shfl_xor(acc1, 1 << t, 64);
                bool  bit   = (lane >> t) & 1;
                float a = bit ? other : acc1;
                float b = bit ? acc1 : other;
                acc1 = fmaf(p, b - a, a);
            }
        }

        // publish per-wave partial(s)
        if (regPair) {
            if (lane == 0) { redA[wv] = acc; redB[wv] = acc1; }
        } else if (st >= 0) {
            // lanes now hold 2 distinct values, keyed by lane bit st
            if (lane == 0)         redA[wv] = acc;   // straggler bit = 0
            if (lane == (1 << st)) redB[wv] = acc;   // straggler bit = 1
        } else {
            if (lane == 0) redA[wv] = acc;
        }
        __syncthreads();

        // ---- wave-tier folds + final: wv bit t <-> c bit 6+t <-> parent 7-t ----
        if (wv == 0) {
            const bool pairAB = (s >= 0) && (s < 4 || s >= 8);
            const int  tw     = (s >= 4 && s < 8) ? (7 - s) : -1;
            float v0 = (lane < NTHR / 64) ? redA[lane] : 0.f;
            float v1 = (pairAB && lane < NTHR / 64) ? redB[lane] : 0.f;
            #pragma unroll
            for (int t = 0; t < 4; ++t) {
                if (t == tw) continue;
                const float p = pv[7 - t];
                {
                    float other = __shfl_xor(v0, 1 << t, 64);
                    bool  bit   = (lane >> t) & 1;
                    float a = bit ? other : v0;
                    float b = bit ? v0 : other;
                    v0 = fmaf(p, b - a, a);
                }
                if (pairAB) {
                    float other = __shfl_xor(v1, 1 << t, 64);
                    bool  bit   = (lane >> t) & 1;
                    float a = bit ? other : v1;
                    float b = bit ? v1 : other;
                    v1 = fmaf(p, b - a, a);
                }
            }
            float res;
            if (s < 0) {
                res = v0;                             // all 14 folded already
            } else {
                float x0, x1;
                if (tw >= 0) { x0 = __shfl(v0, 0, 64); x1 = __shfl(v0, 1 << tw, 64); }
                else         { x0 = v0; x1 = v1; }    // valid at lane 0
                // tight-poll the straggler (uniform address: one request/wave)
                const int sp = sParLds;
                unsigned u = __hip_atomic_load(&flagv[sp], __ATOMIC_RELAXED,
                                               __HIP_MEMORY_SCOPE_AGENT);
                int guard = 0;
                while (u == SENTIN && ++guard < (1 << 23))
                    u = __hip_atomic_load(&flagv[sp], __ATOMIC_RELAXED,
                                          __HIP_MEMORY_SCOPE_AGENT);
                float ps = fminf(fmaxf(__uint_as_float(u), 1e-6f), 1.f - 1e-6f);
                res = fmaf(ps, x1 - x0, x0);          // ONE fma on the critical path
            }
            if (lane == 0) {
                __hip_atomic_store(&flagv[node], __float_as_uint(res),
                                   __ATOMIC_RELAXED, __HIP_MEMORY_SCOPE_AGENT);
                out[node] = res;                      // flag first: it's the consumer
            }
        }

        // rotate prefetch buffer (vmcnt wait lands here; load had a full
        // node interval to arrive)
        #pragma unroll
        for (int m = 0; m < PT; ++m) xs[m] = xn[m];
    }
}

extern "C" void kernel_launch(void* const* d_in, const int* in_sizes, int n_in,
                              void* d_out, int out_size, void* d_ws, size_t ws_size,
                              hipStream_t stream) {
    const float* logits  = (const float*)d_in[0];
    // d_in[1] = configs — encoded analytically in the fold order, unused
    const int*   parents = (const int*)d_in[2];
    // d_in[3] = root_mask — node < 64, unused
    float*    out   = (float*)d_out;
    unsigned* flagv = (unsigned*)d_ws;   // N words

    hipMemsetAsync(flagv, 0x7F, NN * sizeof(unsigned), stream);

    void* args[] = { (void*)&logits, (void*)&parents, (void*)&out, (void*)&flagv };
    hipLaunchCooperativeKernel((const void*)bayes_dag_kernel,
                               dim3(NBLK), dim3(NTHR), args, 0, stream);
}